// Round 4
// baseline (115.894 us; speedup 1.0000x reference)
//
#include <hip/hip_runtime.h>

#define BINS      256
#define BLOCK     256
#define GRID      1024
#define HALF      128          // threads per image within a block
#define MAX_TRIPS 63           // 63*4 = 252 <= 255: u8 counter can't overflow per chunk

// ---- rare fallback paths (exact semantics, global atomics) ----
__device__ __forceinline__ void gbin1(float x, unsigned int* g) {
    if (x >= 0.0f && x <= 1.0f) {
        int bin = (int)floorf(x * 256.0f);       // exact: matches JAX floor(x*256)
        bin = bin > 255 ? 255 : bin;
        atomicAdd(&g[bin], 1u);
    }
}
__device__ __forceinline__ void gbin4(float4 v, unsigned int* g) {
    gbin1(v.x, g); gbin1(v.y, g); gbin1(v.z, g); gbin1(v.w, g);
}

// ---- hot path: thread-private u8 histogram, no atomics ----
__device__ __forceinline__ void rmw4(float4 v, unsigned char* h) {
    const float* f = &v.x;
#pragma unroll
    for (int j = 0; j < 4; ++j) {
        float x = f[j];
        if (x >= 0.0f && x <= 1.0f) {
            int bin = (int)floorf(x * 256.0f);
            bin = bin > 255 ? 255 : bin;
            h[bin] = (unsigned char)(h[bin] + 1u);   // ds_read_u8 + ds_write_b8, thread-exclusive
        }
    }
}

// Pass 1: exact integer histograms. Each thread owns a private 256B u8 histogram
// in LDS (64KB/block). Threads 0..127 bin img1, 128..255 bin img2. Flush is a
// block-cooperative column sum with packed-u16 accumulation, then 4 global
// atomics per dword-column. Zero LDS atomics on the hot path.
__global__ __launch_bounds__(BLOCK, 2) void hist_kernel(
    const float* __restrict__ img1, const float* __restrict__ img2,
    unsigned int* __restrict__ g_h1, unsigned int* __restrict__ g_h2,
    long long n)
{
    __shared__ __align__(16) unsigned char priv[2 * HALF * BINS];   // 64 KB

    const int tid = threadIdx.x;
    const int li  = tid & (HALF - 1);
    const long long n4 = n >> 2;

    const float4* p1 = (const float4*)img1;
    const float4* p2 = (const float4*)img2;
    const float4* src = (tid >= HALF) ? p2 : p1;
    unsigned char* h = &priv[(size_t)tid * BINS];

    // trips per thread (exact for 32*3*512*512: 48)
    const long long tpt = n4 / ((long long)gridDim.x * HALF);

    long long done = 0;
    while (done < tpt) {
        const int chunk = (int)((tpt - done > MAX_TRIPS) ? MAX_TRIPS : (tpt - done));

        // zero private histograms (4096 uint4 / 256 thr = 16 stores each)
        {
            uint4* p = (uint4*)priv;
            for (int i = tid; i < (2 * HALF * BINS) / 16; i += BLOCK)
                p[i] = make_uint4(0u, 0u, 0u, 0u);
        }
        __syncthreads();

        const long long base = (long long)blockIdx.x * tpt + done;
        if (chunk >= 2) {
            // depth-2 prefetch pipeline
            float4 v0 = src[(base + 0) * HALF + li];
            float4 v1 = src[(base + 1) * HALF + li];
            for (int t = 0; t + 2 < chunk; ++t) {
                float4 nv = src[(base + t + 2) * HALF + li];
                rmw4(v0, h);
                v0 = v1; v1 = nv;
            }
            rmw4(v0, h);
            rmw4(v1, h);
        } else if (chunk == 1) {
            float4 v0 = src[base * HALF + li];
            rmw4(v0, h);
        }
        __syncthreads();

        // flush: threads 0..127 each own (image, dword-column d)
        if (tid < 2 * 64) {
            const int imgsel = tid >> 6;
            const int d      = tid & 63;
            const unsigned int* hw = (const unsigned int*)(priv + imgsel * HALF * BINS);
            unsigned int lo = 0u, hi = 0u;        // packed u16 pairs: bins (4d,4d+2) / (4d+1,4d+3)
#pragma unroll 8
            for (int t = 0; t < HALF; ++t) {
                unsigned int w = hw[t * 64 + d];  // bank = d&31: 2-way, free
                lo += w & 0x00FF00FFu;
                hi += (w >> 8) & 0x00FF00FFu;
            }
            unsigned int* g = imgsel ? g_h2 : g_h1;
            unsigned int c0 = lo & 0xFFFFu, c2 = lo >> 16;
            unsigned int c1 = hi & 0xFFFFu, c3 = hi >> 16;
            if (c0) atomicAdd(&g[4 * d + 0], c0);
            if (c1) atomicAdd(&g[4 * d + 1], c1);
            if (c2) atomicAdd(&g[4 * d + 2], c2);
            if (c3) atomicAdd(&g[4 * d + 3], c3);
        }
        done += chunk;
        if (done < tpt) __syncthreads();   // flush reads must finish before next zeroing
    }

    // remainder float4s not covered by the exact decomposition (empty for this shape)
    const long long covered = tpt * (long long)gridDim.x * HALF;
    const long long gtid = (long long)blockIdx.x * BLOCK + tid;
    const long long nthr = (long long)gridDim.x * BLOCK;
    for (long long i = covered + gtid; i < n4; i += nthr) {
        gbin4(p1[i], g_h1);
        gbin4(p2[i], g_h2);
    }
    // scalar tail (n % 4) (empty for this shape)
    for (long long k = (n4 << 2) + gtid; k < n; k += nthr) {
        gbin1(img1[k], g_h1);
        gbin1(img2[k], g_h2);
    }
}

// Pass 2: loss = sum_i |c1[i]/N1 - c2[i]/N2| / 256, double precision.
__global__ __launch_bounds__(BINS) void finalize_kernel(
    const unsigned int* __restrict__ h1, const unsigned int* __restrict__ h2,
    float* __restrict__ out)
{
    const int tid = threadIdx.x;          // one thread per bin
    const unsigned int c1 = h1[tid];
    const unsigned int c2 = h2[tid];

    __shared__ unsigned int s1[4], s2[4];
    __shared__ double sd[4];

    unsigned int r1 = c1, r2 = c2;
#pragma unroll
    for (int off = 32; off > 0; off >>= 1) {
        r1 += __shfl_down(r1, off);
        r2 += __shfl_down(r2, off);
    }
    if ((tid & 63) == 0) { s1[tid >> 6] = r1; s2[tid >> 6] = r2; }
    __syncthreads();

    const double N1 = (double)(s1[0] + s1[1] + s1[2] + s1[3]);
    const double N2 = (double)(s2[0] + s2[1] + s2[2] + s2[3]);

    double d = fabs((double)c1 / N1 - (double)c2 / N2);
#pragma unroll
    for (int off = 32; off > 0; off >>= 1)
        d += __shfl_down(d, off);
    if ((tid & 63) == 0) sd[tid >> 6] = d;
    __syncthreads();

    if (tid == 0) {
        double tot = sd[0] + sd[1] + sd[2] + sd[3];
        out[0] = (float)(tot / (double)BINS);
    }
}

extern "C" void kernel_launch(void* const* d_in, const int* in_sizes, int n_in,
                              void* d_out, int out_size, void* d_ws, size_t ws_size,
                              hipStream_t stream) {
    const float* img1 = (const float*)d_in[0];
    const float* img2 = (const float*)d_in[1];
    const long long n = (long long)in_sizes[0];

    unsigned int* g_h1 = (unsigned int*)d_ws;
    unsigned int* g_h2 = g_h1 + BINS;

    hipMemsetAsync(d_ws, 0, 2 * BINS * sizeof(unsigned int), stream);

    hist_kernel<<<GRID, BLOCK, 0, stream>>>(img1, img2, g_h1, g_h2, n);
    finalize_kernel<<<1, BINS, 0, stream>>>(g_h1, g_h2, (float*)d_out);
}

// Round 5
// 102.947 us; speedup vs baseline: 1.1258x; 1.1258x over previous
//
#include <hip/hip_runtime.h>

#define BINS  256
#define BLOCK 256
#define GRID  2048

// ---- rare fallback paths (exact semantics, global atomics) ----
__device__ __forceinline__ void gbin1(float x, unsigned int* g) {
    if (x >= 0.0f && x <= 1.0f) {
        int bin = (int)floorf(x * 256.0f);       // exact: matches JAX floor(x*256)
        bin = bin > 255 ? 255 : bin;
        atomicAdd(&g[bin], 1u);
    }
}
__device__ __forceinline__ void gbin4(float4 v, unsigned int* g) {
    gbin1(v.x, g); gbin1(v.y, g); gbin1(v.z, g); gbin1(v.w, g);
}

// ---- hot path: ballot bit-slice counting, zero LDS in the loop ----
// One round: 64 values (one per lane). 8 ballots (bin bits) + validity mask.
// Lane owns bins 4*lane..4*lane+3: bin bits 2..7 == lane bits 0..5 (per-lane
// XOR consts e[k]); bin bits 0..1 select among 4 wave-uniform mask combos.
__device__ __forceinline__ void bs_round(float x, const unsigned long long e[6],
                                         unsigned int cnt[4])
{
    const bool valid = (x >= 0.0f) && (x <= 1.0f);
    int bin = (int)(x * 256.0f);                 // trunc == floor for x>=0; masked if invalid
    bin = bin > 255 ? 255 : bin;

    const unsigned long long mv = __ballot(valid);
    const unsigned long long m0 = __ballot(bin & 1);
    const unsigned long long m1 = __ballot(bin & 2);
    const unsigned long long m2 = __ballot(bin & 4);
    const unsigned long long m3 = __ballot(bin & 8);
    const unsigned long long m4 = __ballot(bin & 16);
    const unsigned long long m5 = __ballot(bin & 32);
    const unsigned long long m6 = __ballot(bin & 64);
    const unsigned long long m7 = __ballot(bin & 128);

    const unsigned long long acc = mv
        & (m2 ^ e[0]) & (m3 ^ e[1]) & (m4 ^ e[2])
        & (m5 ^ e[3]) & (m6 ^ e[4]) & (m7 ^ e[5]);

    const unsigned long long nm0 = ~m0, nm1 = ~m1;   // wave-uniform: SALU
    cnt[0] += __popcll(acc & (nm0 & nm1));
    cnt[1] += __popcll(acc & (m0  & nm1));
    cnt[2] += __popcll(acc & (nm0 & m1));
    cnt[3] += __popcll(acc & (m0  & m1));
}

__device__ __forceinline__ void bs4(float4 v, const unsigned long long e[6],
                                    unsigned int cnt[4])
{
    bs_round(v.x, e, cnt);
    bs_round(v.y, e, cnt);
    bs_round(v.z, e, cnt);
    bs_round(v.w, e, cnt);
}

__global__ __launch_bounds__(BLOCK, 6) void hist_kernel(
    const float* __restrict__ img1, const float* __restrict__ img2,
    unsigned int* __restrict__ g_h1, unsigned int* __restrict__ g_h2,
    long long n)
{
    const int tid  = threadIdx.x;
    const int lane = tid & 63;

    unsigned long long e[6];
#pragma unroll
    for (int k = 0; k < 6; ++k)
        e[k] = ((lane >> k) & 1) ? 0ull : ~0ull;

    unsigned int c1[4] = {0u, 0u, 0u, 0u};
    unsigned int c2[4] = {0u, 0u, 0u, 0u};

    const long long n4 = n >> 2;
    const long long stride = (long long)gridDim.x * BLOCK;
    const float4* p1 = (const float4*)img1;
    const float4* p2 = (const float4*)img2;

    long long i = (long long)blockIdx.x * BLOCK + tid;
    const long long trips = n4 / stride;         // uniform across the grid

    if (trips >= 2) {
        // depth-2 prefetch: two iterations' loads in flight during the VALU rounds
        float4 a0 = p1[i],  b0 = p2[i];
        long long ii = i + stride;
        float4 a1 = p1[ii], b1 = p2[ii];
        for (long long t = 0; t + 2 < trips; ++t) {
            const long long in = ii + stride;
            float4 a2 = p1[in], b2 = p2[in];
            bs4(a0, e, c1); bs4(b0, e, c2);
            a0 = a1; b0 = b1; a1 = a2; b1 = b2; ii = in;
        }
        bs4(a0, e, c1); bs4(b0, e, c2);
        bs4(a1, e, c1); bs4(b1, e, c2);
        i = ii + stride;
    } else if (trips == 1) {
        float4 a0 = p1[i], b0 = p2[i];
        bs4(a0, e, c1); bs4(b0, e, c2);
        i += stride;
    }

    // leftover float4s (threads past the uniform trip count; empty for this shape)
    if (i < n4) {
        gbin4(p1[i], g_h1);
        gbin4(p2[i], g_h2);
    }
    // scalar tail (n % 4; empty for this shape)
    {
        const long long gtid = (long long)blockIdx.x * BLOCK + tid;
        for (long long k = (n4 << 2) + gtid; k < n; k += stride)
        {
            gbin1(img1[k], g_h1);
            gbin1(img2[k], g_h2);
        }
    }

    // ---- flush: block-level LDS reduce, then 512 global atomics per block ----
    __shared__ unsigned int bh[2 * BINS];
    for (int k = tid; k < 2 * BINS; k += BLOCK) bh[k] = 0u;
    __syncthreads();
#pragma unroll
    for (int j = 0; j < 4; ++j) {
        if (c1[j]) atomicAdd(&bh[0   + 4 * lane + j], c1[j]);   // 4 waves collide at most 4-way
        if (c2[j]) atomicAdd(&bh[BINS + 4 * lane + j], c2[j]);
    }
    __syncthreads();
    for (int k = tid; k < 2 * BINS; k += BLOCK) {
        const unsigned int v = bh[k];
        if (v) atomicAdd(k < BINS ? &g_h1[k] : &g_h2[k - BINS], v);
    }
}

// Pass 2: loss = sum_i |c1[i]/N1 - c2[i]/N2| / 256, double precision.
__global__ __launch_bounds__(BINS) void finalize_kernel(
    const unsigned int* __restrict__ h1, const unsigned int* __restrict__ h2,
    float* __restrict__ out)
{
    const int tid = threadIdx.x;          // one thread per bin
    const unsigned int c1 = h1[tid];
    const unsigned int c2 = h2[tid];

    __shared__ unsigned int s1[4], s2[4];
    __shared__ double sd[4];

    unsigned int r1 = c1, r2 = c2;
#pragma unroll
    for (int off = 32; off > 0; off >>= 1) {
        r1 += __shfl_down(r1, off);
        r2 += __shfl_down(r2, off);
    }
    if ((tid & 63) == 0) { s1[tid >> 6] = r1; s2[tid >> 6] = r2; }
    __syncthreads();

    const double N1 = (double)(s1[0] + s1[1] + s1[2] + s1[3]);
    const double N2 = (double)(s2[0] + s2[1] + s2[2] + s2[3]);

    double d = fabs((double)c1 / N1 - (double)c2 / N2);
#pragma unroll
    for (int off = 32; off > 0; off >>= 1)
        d += __shfl_down(d, off);
    if ((tid & 63) == 0) sd[tid >> 6] = d;
    __syncthreads();

    if (tid == 0) {
        double tot = sd[0] + sd[1] + sd[2] + sd[3];
        out[0] = (float)(tot / (double)BINS);
    }
}

extern "C" void kernel_launch(void* const* d_in, const int* in_sizes, int n_in,
                              void* d_out, int out_size, void* d_ws, size_t ws_size,
                              hipStream_t stream) {
    const float* img1 = (const float*)d_in[0];
    const float* img2 = (const float*)d_in[1];
    const long long n = (long long)in_sizes[0];

    unsigned int* g_h1 = (unsigned int*)d_ws;
    unsigned int* g_h2 = g_h1 + BINS;

    hipMemsetAsync(d_ws, 0, 2 * BINS * sizeof(unsigned int), stream);

    const long long n4 = n >> 2;
    int blocks = (int)((n4 + BLOCK - 1) / BLOCK);
    if (blocks > GRID) blocks = GRID;
    if (blocks < 1) blocks = 1;

    hist_kernel<<<blocks, BLOCK, 0, stream>>>(img1, img2, g_h1, g_h2, n);
    finalize_kernel<<<1, BINS, 0, stream>>>(g_h1, g_h2, (float*)d_out);
}

// Round 6
// 75.584 us; speedup vs baseline: 1.5333x; 1.3620x over previous
//
#include <hip/hip_runtime.h>

#define BINS  256
#define NCOPY 8
#define BLOCK 256
#define GRID  2048

// ---- rare fallback paths (exact semantics, global atomics) ----
__device__ __forceinline__ void gbin1(float x, unsigned int* g) {
    if (x >= 0.0f && x <= 1.0f) {
        unsigned int bin = (unsigned int)(x * 256.0f);   // trunc==floor for x>=0
        bin = bin > 255u ? 255u : bin;
        atomicAdd(&g[bin], 1u);
    }
}
__device__ __forceinline__ void gbin4(float4 v, unsigned int* g) {
    gbin1(v.x, g); gbin1(v.y, g); gbin1(v.z, g); gbin1(v.w, g);
}

// ---- pipe 1: LDS-atomic binning (DS pipe, ~1 value/cyc/CU) ----
__device__ __forceinline__ void dbin(float x, unsigned int* hc) {
    if (x >= 0.0f && x <= 1.0f) {
        unsigned int bin = (unsigned int)(x * 256.0f);
        bin = bin > 255u ? 255u : bin;
        atomicAdd(&hc[bin * NCOPY], 1u);    // ds_add, fire-and-forget
    }
}

// ---- pipe 2: ballot bit-slice counting (VALU pipe, zero DS) ----
// Lane owns bins 4*lane..4*lane+3; bin bits 2..7 matched against lane bits 0..5.
__device__ __forceinline__ void bs_round(float x, const unsigned long long e[6],
                                         unsigned int cnt[4])
{
    unsigned int bin = (unsigned int)(x * 256.0f);       // v_mul + v_cvt_u32 (clamps)
    bin = bin > 255u ? 255u : bin;                       // v_min_u32

    const unsigned long long mv = __ballot(x >= 0.0f) & __ballot(x <= 1.0f);
    const unsigned long long m0 = __ballot(bin & 1u);
    const unsigned long long m1 = __ballot(bin & 2u);
    const unsigned long long m2 = __ballot(bin & 4u);
    const unsigned long long m3 = __ballot(bin & 8u);
    const unsigned long long m4 = __ballot(bin & 16u);
    const unsigned long long m5 = __ballot(bin & 32u);
    const unsigned long long m6 = __ballot(bin & 64u);
    const unsigned long long m7 = __ballot(bin & 128u);

    const unsigned long long acc = mv
        & (m2 ^ e[0]) & (m3 ^ e[1]) & (m4 ^ e[2])
        & (m5 ^ e[3]) & (m6 ^ e[4]) & (m7 ^ e[5]);

    const unsigned long long nm0 = ~m0, nm1 = ~m1;       // wave-uniform: SALU
    cnt[0] += __popcll(acc & (nm0 & nm1));
    cnt[1] += __popcll(acc & (m0  & nm1));
    cnt[2] += __popcll(acc & (nm0 & m1));
    cnt[3] += __popcll(acc & (m0  & m1));
}

__global__ __launch_bounds__(BLOCK, 4) void hist_kernel(
    const float* __restrict__ img1, const float* __restrict__ img2,
    unsigned int* __restrict__ g_h1, unsigned int* __restrict__ g_h2,
    long long n)
{
    __shared__ unsigned int lh[2][BINS][NCOPY];          // 16 KB, bank-spread copies

    const int tid  = threadIdx.x;
    const int lane = tid & 63;
    const int copy = tid & (NCOPY - 1);

    for (int i = tid; i < 2 * BINS * NCOPY; i += BLOCK)
        ((unsigned int*)lh)[i] = 0u;
    __syncthreads();

    unsigned long long e[6];
#pragma unroll
    for (int k = 0; k < 6; ++k)
        e[k] = ((lane >> k) & 1) ? 0ull : ~0ull;

    unsigned int c1[4] = {0u, 0u, 0u, 0u};
    unsigned int c2[4] = {0u, 0u, 0u, 0u};
    unsigned int* h1c = &lh[0][0][copy];
    unsigned int* h2c = &lh[1][0][copy];

    const long long n4 = n >> 2;
    const long long stride = (long long)gridDim.x * BLOCK;
    const float4* p1 = (const float4*)img1;
    const float4* p2 = (const float4*)img2;

    long long i = (long long)blockIdx.x * BLOCK + tid;
    const long long trips = n4 / stride;                 // uniform across the grid

    // per 8 values: 5 -> ballot (VALU pipe), 3 -> LDS atomic (DS pipe)
#define PROC(a, b)                                                   \
    do {                                                             \
        bs_round((a).x, e, c1); bs_round((a).y, e, c1);              \
        bs_round((a).z, e, c1);                                      \
        bs_round((b).x, e, c2); bs_round((b).y, e, c2);              \
        dbin((a).w, h1c); dbin((b).z, h2c); dbin((b).w, h2c);        \
    } while (0)

    if (trips >= 2) {
        float4 a0 = p1[i],  b0 = p2[i];
        long long ii = i + stride;
        float4 a1 = p1[ii], b1 = p2[ii];
        for (long long t = 0; t + 2 < trips; ++t) {
            const long long in = ii + stride;
            float4 a2 = p1[in], b2 = p2[in];
            PROC(a0, b0);
            a0 = a1; b0 = b1; a1 = a2; b1 = b2; ii = in;
        }
        PROC(a0, b0);
        PROC(a1, b1);
        i = ii + stride;
    } else if (trips == 1) {
        float4 a0 = p1[i], b0 = p2[i];
        PROC(a0, b0);
        i += stride;
    }
#undef PROC

    // leftover float4s (empty for this shape)
    if (i < n4) {
        gbin4(p1[i], g_h1);
        gbin4(p2[i], g_h2);
    }
    // scalar tail (n % 4; empty for this shape)
    {
        const long long gtid = (long long)blockIdx.x * BLOCK + tid;
        for (long long k = (n4 << 2) + gtid; k < n; k += stride) {
            gbin1(img1[k], g_h1);
            gbin1(img2[k], g_h2);
        }
    }

    // ---- flush: merge ballot counters into the LDS copies, reduce, global ----
    __syncthreads();   // all DS-path atomics of this block done
#pragma unroll
    for (int j = 0; j < 4; ++j) {
        if (c1[j]) atomicAdd(&lh[0][4 * lane + j][copy], c1[j]);
        if (c2[j]) atomicAdd(&lh[1][4 * lane + j][copy], c2[j]);
    }
    __syncthreads();

    for (int b = tid; b < BINS; b += BLOCK) {
        unsigned int s1 = 0u, s2 = 0u;
#pragma unroll
        for (int c = 0; c < NCOPY; ++c) { s1 += lh[0][b][c]; s2 += lh[1][b][c]; }
        if (s1) atomicAdd(&g_h1[b], s1);
        if (s2) atomicAdd(&g_h2[b], s2);
    }
}

// Pass 2: loss = sum_i |c1[i]/N1 - c2[i]/N2| / 256, double precision.
__global__ __launch_bounds__(BINS) void finalize_kernel(
    const unsigned int* __restrict__ h1, const unsigned int* __restrict__ h2,
    float* __restrict__ out)
{
    const int tid = threadIdx.x;          // one thread per bin
    const unsigned int c1 = h1[tid];
    const unsigned int c2 = h2[tid];

    __shared__ unsigned int s1[4], s2[4];
    __shared__ double sd[4];

    unsigned int r1 = c1, r2 = c2;
#pragma unroll
    for (int off = 32; off > 0; off >>= 1) {
        r1 += __shfl_down(r1, off);
        r2 += __shfl_down(r2, off);
    }
    if ((tid & 63) == 0) { s1[tid >> 6] = r1; s2[tid >> 6] = r2; }
    __syncthreads();

    const double N1 = (double)(s1[0] + s1[1] + s1[2] + s1[3]);
    const double N2 = (double)(s2[0] + s2[1] + s2[2] + s2[3]);

    double d = fabs((double)c1 / N1 - (double)c2 / N2);
#pragma unroll
    for (int off = 32; off > 0; off >>= 1)
        d += __shfl_down(d, off);
    if ((tid & 63) == 0) sd[tid >> 6] = d;
    __syncthreads();

    if (tid == 0) {
        double tot = sd[0] + sd[1] + sd[2] + sd[3];
        out[0] = (float)(tot / (double)BINS);
    }
}

extern "C" void kernel_launch(void* const* d_in, const int* in_sizes, int n_in,
                              void* d_out, int out_size, void* d_ws, size_t ws_size,
                              hipStream_t stream) {
    const float* img1 = (const float*)d_in[0];
    const float* img2 = (const float*)d_in[1];
    const long long n = (long long)in_sizes[0];

    unsigned int* g_h1 = (unsigned int*)d_ws;
    unsigned int* g_h2 = g_h1 + BINS;

    hipMemsetAsync(d_ws, 0, 2 * BINS * sizeof(unsigned int), stream);

    const long long n4 = n >> 2;
    int blocks = (int)((n4 + BLOCK - 1) / BLOCK);
    if (blocks > GRID) blocks = GRID;
    if (blocks < 1) blocks = 1;

    hist_kernel<<<blocks, BLOCK, 0, stream>>>(img1, img2, g_h1, g_h2, n);
    finalize_kernel<<<1, BINS, 0, stream>>>(g_h1, g_h2, (float*)d_out);
}